// Round 1
// baseline (241.313 us; speedup 1.0000x reference)
//
#include <hip/hip_runtime.h>
#include <hip/hip_bf16.h>
#include <math.h>

#define NW 4096
#define NL 32
#define ND 256
#define ND2 512

typedef __attribute__((ext_vector_type(8))) short short8;
typedef __attribute__((ext_vector_type(4))) float floatx4;

__device__ inline float bfval(short s) {
  union { unsigned u; float f; } v;
  v.u = ((unsigned)(unsigned short)s) << 16;
  return v.f;
}

// ---------------------------------------------------------------------------
// Single persistent kernel, 256 blocks x 256 threads (1 block/CU -> all
// co-resident; LDS 57.6KB, VGPR well under limits, so residency guaranteed).
//
// Phases, separated by device-scope grid barriers:
//   P0  blocks 0..63 : table-direct (chr-w staged+transposed in LDS, no wT)
//       blocks 64..255: sent-w -> Wb bf16 transform; block 255: u guard rows
//   P1  char conv + word-emb gather -> u0           (256 jobs, 1/block)
//   P2  sent conv MFMA, 64co x 128t per block        (256 jobs, 1/block)
//   P3  fc1: 4 outputs/block                         (256 blocks)
//   P4  fc2: block 0 only
//
// Barrier: monotonic counter in ws, re-zeroed each launch by hipMemsetAsync.
// Arrive = agent-scope RELEASE fetch_add (writes back XCD L2); spin on
// RELAXED agent loads (no L2-invalidate storm); one ACQUIRE fence on exit.
// ---------------------------------------------------------------------------

union SMem {
  struct { float w[256][49]; float e[2][256]; } tab;          // 52.2 KB
  struct { short T[3 * 128 * 64]; int wic[64 * 32]; int wid[64]; } chr; // 57.6 KB
  struct { short As[64 * 64]; short Bs[128 * 64]; float red[4][32]; } sent; // 24.6 KB
  struct { float r[512]; } fc;                                 // 2 KB
};

__device__ __forceinline__ void gbar(int* ctr, int expect) {
  __syncthreads();
  if (threadIdx.x == 0) {
    __hip_atomic_fetch_add(ctr, 1, __ATOMIC_RELEASE, __HIP_MEMORY_SCOPE_AGENT);
    while (__hip_atomic_load(ctr, __ATOMIC_RELAXED, __HIP_MEMORY_SCOPE_AGENT) < expect)
      __builtin_amdgcn_s_sleep(8);
    __builtin_amdgcn_fence(__ATOMIC_ACQUIRE, "agent");
  }
  __syncthreads();
}

__global__ __launch_bounds__(256) void fused_kernel(
    const int* __restrict__ words, const int* __restrict__ wic,
    const float* __restrict__ word_emb, const float* __restrict__ chr_emb,
    const float* __restrict__ conv_chr_w, const float* __restrict__ conv_chr_b,
    const float* __restrict__ conv_sent_w, const float* __restrict__ conv_sent_b,
    const float* __restrict__ w1, const float* __restrict__ b1,
    const float* __restrict__ w2, const float* __restrict__ b2,
    int* __restrict__ ctr, float* __restrict__ part, float* __restrict__ h_buf,
    short* __restrict__ Tb, short* __restrict__ u_base,
    __hip_bfloat16* __restrict__ Wb, float* __restrict__ out) {
  __shared__ SMem S;
  const int b = blockIdx.x;
  const int tid = threadIdx.x;

  // ---------------- P0 ----------------
  if (b >= 64) {
    // sent-w transform: 192 blocks x 4096 elems
    int base = (b - 64) * 4096;
#pragma unroll
    for (int i = 0; i < 16; ++i) {
      int idx = base + i * 256 + tid;
      float v = conv_sent_w[idx];
      int co = idx / 1536;
      int rem = idx - co * 1536;
      int ci = rem / 3;
      int k = rem - ci * 3;
      Wb[k * 262144 + co * 512 + ci] = __float2bfloat16(v);
    }
    if (b == 255) {  // u guard rows (t=-1, t=4096)
      u_base[tid] = 0; u_base[tid + 256] = 0;
      u_base[4097 * 512 + tid] = 0; u_base[4097 * 512 + tid + 256] = 0;
    }
  } else {
    // table-direct: block handles c-pair c0=b*2, all 3 k, threads = co.
    // T[k][c][co] = sum_ci emb[c][ci] * chr_w[co][ci][k]  (same fmaf chain
    // order as the old wT path -> bit-identical)
    const int c0 = b * 2;
    const int co = tid;
    S.tab.e[0][tid] = chr_emb[(c0 + 0) * 256 + tid];
    S.tab.e[1][tid] = chr_emb[(c0 + 1) * 256 + tid];
    float acc[2][3] = {};
    for (int chk = 0; chk < 16; ++chk) {
      const int ci0 = chk * 16;
      __syncthreads();
      // stage [256 co][16 ci x 3 k] chunk, coalesced along (ci,k)
#pragma unroll 8
      for (int i = 0; i < 48; ++i) {
        int f = tid + i * 256;
        int wco = f / 48;
        int j = f - wco * 48;
        S.tab.w[wco][j] = conv_chr_w[wco * 768 + ci0 * 3 + j];
      }
      __syncthreads();
#pragma unroll
      for (int ci = 0; ci < 16; ++ci) {
        float t_w0 = S.tab.w[co][ci * 3 + 0];
        float t_w1 = S.tab.w[co][ci * 3 + 1];
        float t_w2 = S.tab.w[co][ci * 3 + 2];
        float e0 = S.tab.e[0][ci0 + ci];
        float e1 = S.tab.e[1][ci0 + ci];
        acc[0][0] = fmaf(e0, t_w0, acc[0][0]);
        acc[0][1] = fmaf(e0, t_w1, acc[0][1]);
        acc[0][2] = fmaf(e0, t_w2, acc[0][2]);
        acc[1][0] = fmaf(e1, t_w0, acc[1][0]);
        acc[1][1] = fmaf(e1, t_w1, acc[1][1]);
        acc[1][2] = fmaf(e1, t_w2, acc[1][2]);
      }
    }
    __hip_bfloat16* TbB = (__hip_bfloat16*)Tb;
    const int tbase = ((co >> 6) * 3) * 8192 + (co & 63);
#pragma unroll
    for (int k = 0; k < 3; ++k) {
      TbB[tbase + k * 8192 + (c0 + 0) * 64] = __float2bfloat16(acc[0][k]);
      TbB[tbase + k * 8192 + (c0 + 1) * 64] = __float2bfloat16(acc[1][k]);
    }
  }
  gbar(ctr, 256);

  // ---------------- P1: char conv + word gather ----------------
  {
    const int ct = b >> 6;
    const int w0c = (b & 63) * 64;
    const uint4* src = (const uint4*)(Tb + ct * 24576);
    uint4* dst = (uint4*)S.chr.T;
#pragma unroll
    for (int i = 0; i < 12; ++i) dst[tid + i * 256] = src[tid + i * 256];
    const int4* wsrc = (const int4*)(wic + w0c * 32);
    int4* wdst = (int4*)S.chr.wic;
    wdst[tid] = wsrc[tid];
    wdst[tid + 256] = wsrc[tid + 256];
    if (tid < 64) S.chr.wid[tid] = words[w0c + tid];
    __syncthreads();
    const int co_l = tid & 63;
    const int slot = tid >> 6;
    const float bb = conv_chr_b[ct * 64 + co_l];
    const short* T0p = S.chr.T;
    const short* T1p = S.chr.T + 8192;
    const short* T2p = S.chr.T + 16384;
    __hip_bfloat16* u0 = (__hip_bfloat16*)(u_base + 512);
    for (int wi = 0; wi < 16; ++wi) {
      int wl = slot * 16 + wi;
      u0[(w0c + wl) * ND2 + ct * 64 + co_l] =
          __float2bfloat16(word_emb[S.chr.wid[wl] * ND + ct * 64 + co_l]);
      const int* ch = S.chr.wic + wl * 32;
      float mx = -INFINITY;
#pragma unroll
      for (int t = 0; t < NL; ++t) {
        float sv = bfval(T1p[ch[t] * 64 + co_l]);
        if (t > 0) sv += bfval(T0p[ch[t - 1] * 64 + co_l]);
        if (t < NL - 1) sv += bfval(T2p[ch[t + 1] * 64 + co_l]);
        mx = fmaxf(mx, sv);
      }
      u0[(w0c + wl) * ND2 + ND + ct * 64 + co_l] = __float2bfloat16(mx + bb);
    }
  }
  gbar(ctr, 512);

  // ---------------- P2: sent conv MFMA, 64co x 128t per block ----------------
  {
    const int co0 = (b & 7) * 64;
    const int T0 = (b >> 3) * 128;
    const int wave = tid >> 6, lane = tid & 63;
    const int wy = wave >> 1, wx = wave & 1;
    const int m = lane & 15, q = lane >> 4;
    floatx4 acc[2][4];
#pragma unroll
    for (int i = 0; i < 2; ++i)
#pragma unroll
      for (int j = 0; j < 4; ++j) acc[i][j] = (floatx4){0.f, 0.f, 0.f, 0.f};

    int aoff[2][2], boff[2][4];
#pragma unroll
    for (int kk = 0; kk < 2; ++kk) {
#pragma unroll
      for (int i = 0; i < 2; ++i) {
        int row = wy * 32 + i * 16 + m;
        aoff[kk][i] = row * 64 + (((kk * 4 + q) ^ (row & 7)) * 8);
      }
#pragma unroll
      for (int j = 0; j < 4; ++j) {
        int row = (j >> 1) * 64 + wx * 32 + (j & 1) * 16 + m;
        boff[kk][j] = row * 64 + (((kk * 4 + q) ^ (row & 7)) * 8);
      }
    }
    const int sc = tid & 7, sr = tid >> 3;
    const int swc = (sc ^ (sr & 7)) * 8;
    const short* WbS = (const short*)Wb;
    const short* uS = u_base + 512;

    uint4 ra0, ra1, rb0, rb1, rb2, rb3;
    auto LOADS = [&](int s2) {
      int k = s2 >> 3, ci0 = (s2 & 7) << 6;
      const short* WbK = WbS + k * 262144 + (co0 + sr) * 512 + ci0 + sc * 8;
      const short* uK = uS + (T0 + sr + k - 1) * 512 + ci0 + sc * 8;
      ra0 = *(const uint4*)(WbK);
      ra1 = *(const uint4*)(WbK + 32 * 512);
      rb0 = *(const uint4*)(uK);
      rb1 = *(const uint4*)(uK + 32 * 512);
      rb2 = *(const uint4*)(uK + 64 * 512);
      rb3 = *(const uint4*)(uK + 96 * 512);
    };
    LOADS(0);
    for (int s = 0; s < 24; ++s) {
      *(uint4*)&S.sent.As[sr * 64 + swc] = ra0;
      *(uint4*)&S.sent.As[(sr + 32) * 64 + swc] = ra1;
      *(uint4*)&S.sent.Bs[sr * 64 + swc] = rb0;
      *(uint4*)&S.sent.Bs[(sr + 32) * 64 + swc] = rb1;
      *(uint4*)&S.sent.Bs[(sr + 64) * 64 + swc] = rb2;
      *(uint4*)&S.sent.Bs[(sr + 96) * 64 + swc] = rb3;
      __syncthreads();
      if (s < 23) LOADS(s + 1);  // next-step global loads hide under MFMAs
#pragma unroll
      for (int kk = 0; kk < 2; ++kk) {
        short8 av0 = *(const short8*)&S.sent.As[aoff[kk][0]];
        short8 av1 = *(const short8*)&S.sent.As[aoff[kk][1]];
        short8 bv0 = *(const short8*)&S.sent.Bs[boff[kk][0]];
        short8 bv1 = *(const short8*)&S.sent.Bs[boff[kk][1]];
        short8 bv2 = *(const short8*)&S.sent.Bs[boff[kk][2]];
        short8 bv3 = *(const short8*)&S.sent.Bs[boff[kk][3]];
        acc[0][0] = __builtin_amdgcn_mfma_f32_16x16x32_bf16(av0, bv0, acc[0][0], 0, 0, 0);
        acc[0][1] = __builtin_amdgcn_mfma_f32_16x16x32_bf16(av0, bv1, acc[0][1], 0, 0, 0);
        acc[0][2] = __builtin_amdgcn_mfma_f32_16x16x32_bf16(av0, bv2, acc[0][2], 0, 0, 0);
        acc[0][3] = __builtin_amdgcn_mfma_f32_16x16x32_bf16(av0, bv3, acc[0][3], 0, 0, 0);
        acc[1][0] = __builtin_amdgcn_mfma_f32_16x16x32_bf16(av1, bv0, acc[1][0], 0, 0, 0);
        acc[1][1] = __builtin_amdgcn_mfma_f32_16x16x32_bf16(av1, bv1, acc[1][1], 0, 0, 0);
        acc[1][2] = __builtin_amdgcn_mfma_f32_16x16x32_bf16(av1, bv2, acc[1][2], 0, 0, 0);
        acc[1][3] = __builtin_amdgcn_mfma_f32_16x16x32_bf16(av1, bv3, acc[1][3], 0, 0, 0);
      }
      __syncthreads();
    }
    // epilogue: max over 128 t within block
#pragma unroll
    for (int i = 0; i < 2; ++i)
#pragma unroll
      for (int r = 0; r < 4; ++r) {
        float x = fmaxf(fmaxf(acc[i][0][r], acc[i][1][r]),
                        fmaxf(acc[i][2][r], acc[i][3][r]));
#pragma unroll
        for (int off = 1; off < 16; off <<= 1)
          x = fmaxf(x, __shfl_xor(x, off, 64));
        if (m == 0) S.sent.red[wave][i * 16 + q * 4 + r] = x;
      }
    __syncthreads();
    if (tid < 64) {
      int whalf = tid >> 5;
      float v = fmaxf(S.sent.red[whalf * 2 + 0][tid & 31],
                      S.sent.red[whalf * 2 + 1][tid & 31]);
      part[(co0 + tid) * 32 + (b >> 3)] = v;
    }
  }
  gbar(ctr, 768);

  // ---------------- P3: fc1 (4 outputs/block) ----------------
  {
#pragma unroll
    for (int rep = 0; rep < 2; ++rep) {
      int row = tid + rep * 256;
      const float4* p = (const float4*)(part + row * 32);
      float mm = -INFINITY;
#pragma unroll
      for (int j = 0; j < 8; ++j) {
        float4 v = p[j];
        mm = fmaxf(mm, fmaxf(fmaxf(v.x, v.y), fmaxf(v.z, v.w)));
      }
      S.fc.r[row] = mm + conv_sent_b[row];
    }
    __syncthreads();
    const int wave = tid >> 6, lane = tid & 63;
    const int o = b * 4 + wave;
    const float4* wv = (const float4*)(w1 + o * 512 + lane * 8);
    const float4* rv = (const float4*)(S.fc.r + lane * 8);
    float4 wv0 = wv[0], wv1 = wv[1];
    float4 rv0 = rv[0], rv1 = rv[1];
    float acc = wv0.x * rv0.x + wv0.y * rv0.y + wv0.z * rv0.z + wv0.w * rv0.w +
                wv1.x * rv1.x + wv1.y * rv1.y + wv1.z * rv1.z + wv1.w * rv1.w;
#pragma unroll
    for (int off = 32; off >= 1; off >>= 1) acc += __shfl_down(acc, off, 64);
    if (lane == 0) h_buf[o] = tanhf(acc + b1[o]);
  }
  gbar(ctr, 1024);

  // ---------------- P4: fc2 (block 0) ----------------
  if (b == 0 && tid < 128) {
    const int o = tid >> 6;
    const int lane = tid & 63;
    float acc2 = 0.f;
#pragma unroll
    for (int j = 0; j < 16; ++j)
      acc2 = fmaf(w2[o * 1024 + lane + j * 64], h_buf[lane + j * 64], acc2);
#pragma unroll
    for (int off = 32; off >= 1; off >>= 1) acc2 += __shfl_down(acc2, off, 64);
    if (lane == 0) out[o] = acc2 + b2[o];
  }
}

extern "C" void kernel_launch(void* const* d_in, const int* in_sizes, int n_in,
                              void* d_out, int out_size, void* d_ws, size_t ws_size,
                              hipStream_t stream) {
  const int*   words       = (const int*)d_in[0];
  const int*   wic         = (const int*)d_in[1];
  const float* word_emb    = (const float*)d_in[2];
  const float* chr_emb     = (const float*)d_in[3];
  const float* conv_chr_w  = (const float*)d_in[4];
  const float* conv_chr_b  = (const float*)d_in[5];
  const float* conv_sent_w = (const float*)d_in[6];
  const float* conv_sent_b = (const float*)d_in[7];
  const float* w1          = (const float*)d_in[8];
  const float* b1          = (const float*)d_in[9];
  const float* w2          = (const float*)d_in[10];
  const float* b2          = (const float*)d_in[11];
  float* out = (float*)d_out;

  float* ws    = (float*)d_ws;
  int*   ctr   = (int*)ws;                  // 16B (zeroed each launch)
  float* part  = ws + 4;                    // 512*32 f
  float* h_buf = part + 16384;              // 1024 f
  short* Tb    = (short*)(h_buf + 1024);    // 98304 bf16
  short* u_base = Tb + 98304;               // 4098*512 bf16 (guards at ends)
  __hip_bfloat16* Wb = (__hip_bfloat16*)(u_base + 4098 * 512);  // 3*512*512 bf16

  hipMemsetAsync(ctr, 0, 16, stream);
  fused_kernel<<<256, 256, 0, stream>>>(words, wic, word_emb, chr_emb,
      conv_chr_w, conv_chr_b, conv_sent_w, conv_sent_b, w1, b1, w2, b2,
      ctr, part, h_buf, Tb, u_base, Wb, out);
}

// Round 2
// 184.741 us; speedup vs baseline: 1.3062x; 1.3062x over previous
//
#include <hip/hip_runtime.h>
#include <hip/hip_bf16.h>
#include <math.h>

#define NW 4096
#define NL 32
#define ND 256
#define ND2 512

typedef __attribute__((ext_vector_type(8))) short short8;
typedef __attribute__((ext_vector_type(4))) float floatx4;

__device__ inline float bitsf(unsigned u) {
  union { unsigned u; float f; } v;
  v.u = u;
  return v.f;
}

// ---------------------------------------------------------------------------
// ws layout:
//   part  fp32 [512][64]
//   h     fp32 [1024]
//   Tb    bf16 [4 cotile][3 k][128 c][64 co] (char conv tables)
//   u     bf16 [4098][512]  (guard rows at both ends)
//   Wb    bf16 [3][512 co][512 ci]           (sent conv w)
// No wT: table kernel reads conv_chr_w directly via LDS-staged chunks.
// ---------------------------------------------------------------------------

// K1: merged prep + table-direct. 3137 blocks.
//   b in [0,64):    table-direct, c-pair c0=b*2 (verified bit-exact in R1)
//   b in [64,3136): sent-w -> Wb bf16 transform, 1 elem/thread
//   b == 3136:      u guard rows
__global__ __launch_bounds__(256) void prep_table_kernel(
    const float* __restrict__ conv_sent_w, const float* __restrict__ conv_chr_w,
    const float* __restrict__ chr_emb, __hip_bfloat16* __restrict__ Wb,
    __hip_bfloat16* __restrict__ Tb, short* __restrict__ u_base) {
  __shared__ float s_w[256][49];
  __shared__ float s_e[2][256];
  const int b = blockIdx.x;
  const int tid = threadIdx.x;
  if (b >= 64) {
    if (b < 3136) {
      int idx = (b - 64) * 256 + tid;
      float v = conv_sent_w[idx];
      int co = idx / 1536;
      int rem = idx - co * 1536;
      int ci = rem / 3;
      int k = rem - ci * 3;
      Wb[k * 262144 + co * 512 + ci] = __float2bfloat16(v);
    } else {
      u_base[tid] = 0; u_base[tid + 256] = 0;
      u_base[4097 * 512 + tid] = 0; u_base[4097 * 512 + tid + 256] = 0;
    }
    return;
  }
  // table-direct: T[k][c][co] = sum_ci emb[c][ci] * chr_w[co][ci][k]
  // (ci ascending fmaf chain -> bit-identical to the old wT path)
  const int c0 = b * 2;
  const int co = tid;
  s_e[0][tid] = chr_emb[(c0 + 0) * 256 + tid];
  s_e[1][tid] = chr_emb[(c0 + 1) * 256 + tid];
  float acc[2][3] = {};
  for (int chk = 0; chk < 16; ++chk) {
    const int ci0 = chk * 16;
    __syncthreads();
    // stage [256 co][16 ci x 3 k] chunk, coalesced along (ci,k)
#pragma unroll 8
    for (int i = 0; i < 48; ++i) {
      int f = tid + i * 256;
      int wco = f / 48;
      int j = f - wco * 48;
      s_w[wco][j] = conv_chr_w[wco * 768 + ci0 * 3 + j];
    }
    __syncthreads();
#pragma unroll
    for (int ci = 0; ci < 16; ++ci) {
      float t_w0 = s_w[co][ci * 3 + 0];
      float t_w1 = s_w[co][ci * 3 + 1];
      float t_w2 = s_w[co][ci * 3 + 2];
      float e0 = s_e[0][ci0 + ci];
      float e1 = s_e[1][ci0 + ci];
      acc[0][0] = fmaf(e0, t_w0, acc[0][0]);
      acc[0][1] = fmaf(e0, t_w1, acc[0][1]);
      acc[0][2] = fmaf(e0, t_w2, acc[0][2]);
      acc[1][0] = fmaf(e1, t_w0, acc[1][0]);
      acc[1][1] = fmaf(e1, t_w1, acc[1][1]);
      acc[1][2] = fmaf(e1, t_w2, acc[1][2]);
    }
  }
  const int tbase = ((co >> 6) * 3) * 8192 + (co & 63);
#pragma unroll
  for (int k = 0; k < 3; ++k) {
    Tb[tbase + k * 8192 + (c0 + 0) * 64] = __float2bfloat16(acc[0][k]);
    Tb[tbase + k * 8192 + (c0 + 1) * 64] = __float2bfloat16(acc[1][k]);
  }
}

// K2: char conv + word-emb gather. 512 blocks (ct = b>>7, 32-word chunk),
// 2 blocks/CU (52.4 KB LDS). Conv reads table as paired-co b32 loads:
// lane = co-pair (32 lanes), half-waves = 2 words in flight.
__global__ __launch_bounds__(256) void char_word_kernel(
    const int* __restrict__ words, const int* __restrict__ wic,
    const __hip_bfloat16* __restrict__ Tb, const float* __restrict__ word_emb,
    const float* __restrict__ bias, __hip_bfloat16* __restrict__ u0) {
  __shared__ short sT[3 * 128 * 64];   // 48 KB
  __shared__ int s_wic[32 * 32];       // 4 KB
  __shared__ int s_wid[32];
  const int ct = blockIdx.x >> 7;
  const int w0 = (blockIdx.x & 127) * 32;
  const int tid = threadIdx.x;
  {
    const uint4* src = (const uint4*)((const short*)Tb + ct * 24576);
    uint4* dst = (uint4*)sT;
#pragma unroll
    for (int i = 0; i < 12; ++i) dst[tid + i * 256] = src[tid + i * 256];
    ((int4*)s_wic)[tid] = ((const int4*)(wic + w0 * 32))[tid];
    if (tid < 32) s_wid[tid] = words[w0 + tid];
  }
  __syncthreads();
  // word-emb gather: 4 slots x 8 words, coalesced 256B per word
  {
    const int co_l = tid & 63, slot = tid >> 6;
#pragma unroll
    for (int wi = 0; wi < 8; ++wi) {
      int wl = slot * 8 + wi;
      u0[(w0 + wl) * ND2 + ct * 64 + co_l] =
          __float2bfloat16(word_emb[s_wid[wl] * ND + ct * 64 + co_l]);
    }
  }
  const int wave = tid >> 6, lane = tid & 63;
  const int half = lane >> 5, co2 = (lane & 31) * 2;
  const float2 bb = *(const float2*)&bias[ct * 64 + co2];
  const short* T0p = sT;
  const short* T1p = sT + 8192;
  const short* T2p = sT + 16384;
#pragma unroll
  for (int p = 0; p < 4; ++p) {
    const int wl = wave * 8 + p * 2 + half;
    // pull this word's 32 char ids into registers (8x ds_read_b128)
    int chv[32];
    const int4* c4 = (const int4*)(s_wic + wl * 32);
#pragma unroll
    for (int j = 0; j < 8; ++j) {
      int4 cc = c4[j];
      chv[4 * j + 0] = cc.x; chv[4 * j + 1] = cc.y;
      chv[4 * j + 2] = cc.z; chv[4 * j + 3] = cc.w;
    }
    float m0 = -INFINITY, m1 = -INFINITY;
#pragma unroll
    for (int t = 0; t < NL; ++t) {
      // same per-co add order as before: T1, then T0, then T2 -> bit-exact
      unsigned v1 = *(const unsigned*)&T1p[chv[t] * 64 + co2];
      float s0 = bitsf(v1 << 16);
      float s1 = bitsf(v1 & 0xffff0000u);
      if (t > 0) {
        unsigned v0 = *(const unsigned*)&T0p[chv[t - 1] * 64 + co2];
        s0 += bitsf(v0 << 16);
        s1 += bitsf(v0 & 0xffff0000u);
      }
      if (t < NL - 1) {
        unsigned v2 = *(const unsigned*)&T2p[chv[t + 1] * 64 + co2];
        s0 += bitsf(v2 << 16);
        s1 += bitsf(v2 & 0xffff0000u);
      }
      m0 = fmaxf(m0, s0);
      m1 = fmaxf(m1, s1);
    }
    __hip_bfloat162 hh;
    hh.x = __float2bfloat16(m0 + bb.x);
    hh.y = __float2bfloat16(m1 + bb.y);
    *(__hip_bfloat162*)&u0[(w0 + wl) * ND2 + ND + ct * 64 + co2] = hh;
  }
}

// K3: sentence conv GEMM (round-0 proven: 512 blocks, 2/CU, 0-conflict swizzle)
__global__ __launch_bounds__(256, 2) void sent_conv_mfma(
    const __hip_bfloat16* __restrict__ u0,
    const __hip_bfloat16* __restrict__ Wb,
    float* __restrict__ partial) {
  __shared__ short As[64 * 64];
  __shared__ short Bs[64 * 64];
  __shared__ float sm[4][32];
  const int tid = threadIdx.x;
  const int t0 = blockIdx.x * 64;
  const int co0 = blockIdx.y * 64;
  const int wave = tid >> 6, lane = tid & 63;
  const int wy = wave >> 1, wx = wave & 1;
  const int m = lane & 15, q = lane >> 4;

  floatx4 acc[2][2];
#pragma unroll
  for (int i = 0; i < 2; ++i)
#pragma unroll
    for (int j = 0; j < 2; ++j) acc[i][j] = (floatx4){0.f, 0.f, 0.f, 0.f};

  int aoff[2][2], boff[2][2];
#pragma unroll
  for (int kk = 0; kk < 2; ++kk) {
#pragma unroll
    for (int i = 0; i < 2; ++i) {
      int row = wy * 32 + i * 16 + m;
      aoff[kk][i] = row * 64 + (((kk * 4 + q) ^ (row & 7)) * 8);
      row = wx * 32 + i * 16 + m;
      boff[kk][i] = row * 64 + (((kk * 4 + q) ^ (row & 7)) * 8);
    }
  }

  const int sc = tid & 7, sr = tid >> 3;
  const int swc = (sc ^ (sr & 7)) * 8;
  const short* WbS = (const short*)Wb;
  const short* uS = (const short*)u0;

  for (int s = 0; s < 24; ++s) {
    int k = s >> 3, ci0 = (s & 7) << 6;
    const short* WbK = WbS + k * 262144 + (co0 + sr) * 512 + ci0 + sc * 8;
    const short* uK = uS + (t0 + sr + k - 1) * 512 + ci0 + sc * 8;
    uint4 a0 = *(const uint4*)(WbK);
    uint4 a1 = *(const uint4*)(WbK + 32 * 512);
    uint4 b0 = *(const uint4*)(uK);
    uint4 b1 = *(const uint4*)(uK + 32 * 512);
    *(uint4*)&As[sr * 64 + swc] = a0;
    *(uint4*)&As[(sr + 32) * 64 + swc] = a1;
    *(uint4*)&Bs[sr * 64 + swc] = b0;
    *(uint4*)&Bs[(sr + 32) * 64 + swc] = b1;
    __syncthreads();
#pragma unroll
    for (int kk = 0; kk < 2; ++kk) {
      short8 av0 = *(const short8*)&As[aoff[kk][0]];
      short8 av1 = *(const short8*)&As[aoff[kk][1]];
      short8 bv0 = *(const short8*)&Bs[boff[kk][0]];
      short8 bv1 = *(const short8*)&Bs[boff[kk][1]];
      acc[0][0] = __builtin_amdgcn_mfma_f32_16x16x32_bf16(av0, bv0, acc[0][0], 0, 0, 0);
      acc[0][1] = __builtin_amdgcn_mfma_f32_16x16x32_bf16(av0, bv1, acc[0][1], 0, 0, 0);
      acc[1][0] = __builtin_amdgcn_mfma_f32_16x16x32_bf16(av1, bv0, acc[1][0], 0, 0, 0);
      acc[1][1] = __builtin_amdgcn_mfma_f32_16x16x32_bf16(av1, bv1, acc[1][1], 0, 0, 0);
    }
    __syncthreads();
  }

#pragma unroll
  for (int i = 0; i < 2; ++i)
#pragma unroll
    for (int r = 0; r < 4; ++r) {
      float x = fmaxf(acc[i][0][r], acc[i][1][r]);
#pragma unroll
      for (int off = 1; off < 16; off <<= 1)
        x = fmaxf(x, __shfl_xor(x, off, 64));
      if (m == 0) sm[wave][i * 16 + q * 4 + r] = x;
    }
  __syncthreads();
  if (tid < 64) {
    int whalf = tid >> 5;
    float v = fmaxf(sm[whalf * 2 + 0][tid & 31], sm[whalf * 2 + 1][tid & 31]);
    partial[(co0 + tid) * 64 + blockIdx.x] = v;
  }
}

// K4: fc1 with fused r-reduction. grid 128 x 512 threads.
__global__ __launch_bounds__(512) void fc1_kernel(
    const float* __restrict__ partial, const float* __restrict__ bs,
    const float* __restrict__ w1, const float* __restrict__ b1,
    float* __restrict__ h) {
  __shared__ float s_r[512];
  int tid = threadIdx.x;
  {
    const float4* p = (const float4*)(partial + tid * 64);
    float mm = -INFINITY;
#pragma unroll
    for (int j = 0; j < 16; ++j) {
      float4 v = p[j];
      mm = fmaxf(mm, fmaxf(fmaxf(v.x, v.y), fmaxf(v.z, v.w)));
    }
    s_r[tid] = mm + bs[tid];
  }
  __syncthreads();
  int wave = tid >> 6, lane = tid & 63;
  int o = blockIdx.x * 8 + wave;
  const float4* wv = (const float4*)(w1 + o * 512 + lane * 8);
  const float4* rv = (const float4*)(s_r + lane * 8);
  float4 w0 = wv[0], w1v = wv[1];
  float4 r0 = rv[0], r1 = rv[1];
  float acc = w0.x * r0.x + w0.y * r0.y + w0.z * r0.z + w0.w * r0.w +
              w1v.x * r1.x + w1v.y * r1.y + w1v.z * r1.z + w1v.w * r1.w;
#pragma unroll
  for (int off = 32; off >= 1; off >>= 1) acc += __shfl_down(acc, off, 64);
  if (lane == 0) h[o] = tanhf(acc + b1[o]);
}

__global__ __launch_bounds__(128) void fc2_kernel(
    const float* __restrict__ h, const float* __restrict__ w2,
    const float* __restrict__ b2, float* __restrict__ out) {
  int tid = threadIdx.x;
  int o = tid >> 6;
  int lane = tid & 63;
  float acc = 0.f;
#pragma unroll
  for (int j = 0; j < 16; ++j)
    acc = fmaf(w2[o * 1024 + lane + j * 64], h[lane + j * 64], acc);
#pragma unroll
  for (int off = 32; off >= 1; off >>= 1) acc += __shfl_down(acc, off, 64);
  if (lane == 0) out[o] = acc + b2[o];
}

extern "C" void kernel_launch(void* const* d_in, const int* in_sizes, int n_in,
                              void* d_out, int out_size, void* d_ws, size_t ws_size,
                              hipStream_t stream) {
  const int*   words       = (const int*)d_in[0];
  const int*   wic         = (const int*)d_in[1];
  const float* word_emb    = (const float*)d_in[2];
  const float* chr_emb     = (const float*)d_in[3];
  const float* conv_chr_w  = (const float*)d_in[4];
  const float* conv_chr_b  = (const float*)d_in[5];
  const float* conv_sent_w = (const float*)d_in[6];
  const float* conv_sent_b = (const float*)d_in[7];
  const float* w1          = (const float*)d_in[8];
  const float* b1          = (const float*)d_in[9];
  const float* w2          = (const float*)d_in[10];
  const float* b2          = (const float*)d_in[11];
  float* out = (float*)d_out;

  float* ws    = (float*)d_ws;
  float* part  = ws;                        // 32768 f
  float* h_buf = part + 32768;              // 1024 f
  short* Tb    = (short*)(h_buf + 1024);    // 98304 bf16
  short* u_base = Tb + 98304;               // 4098*512 bf16
  __hip_bfloat16* u0 = (__hip_bfloat16*)(u_base + 512);
  __hip_bfloat16* Wb = (__hip_bfloat16*)(u_base + 4098 * 512);

  prep_table_kernel<<<3137, 256, 0, stream>>>(conv_sent_w, conv_chr_w, chr_emb,
                                              Wb, (__hip_bfloat16*)Tb, u_base);
  char_word_kernel<<<512, 256, 0, stream>>>(words, wic, (const __hip_bfloat16*)Tb,
                                            word_emb, conv_chr_b, u0);
  sent_conv_mfma<<<dim3(64, 8), 256, 0, stream>>>(u0, Wb, part);
  fc1_kernel<<<128, 512, 0, stream>>>(part, conv_sent_b, w1, b1, h_buf);
  fc2_kernel<<<1, 128, 0, stream>>>(h_buf, w2, b2, out);
}

// Round 3
// 166.690 us; speedup vs baseline: 1.4477x; 1.1083x over previous
//
#include <hip/hip_runtime.h>
#include <hip/hip_bf16.h>
#include <math.h>

#define NW 4096
#define NL 32
#define ND 256
#define ND2 512

typedef __attribute__((ext_vector_type(8))) short short8;
typedef __attribute__((ext_vector_type(4))) float floatx4;

__device__ inline float bitsf(unsigned u) {
  union { unsigned u; float f; } v;
  v.u = u;
  return v.f;
}

// ---------------------------------------------------------------------------
// ws layout:
//   part  fp32 [512][64]
//   h     fp32 [1024]
//   Tb    bf16 [4 cotile][3 k][128 c][64 co] (char conv tables)
//   u     bf16 [4098][512]  (guard rows at both ends)
//   Wb    bf16 [3][512 co][512 ci]           (sent conv w)
// No wT: table blocks read conv_chr_w per-thread-row (contiguous 3KB/thread),
// barrier-free, pipelined by unroll — fixes R2's latency-serial staging.
// ---------------------------------------------------------------------------

// K1: merged prep + table-direct. 3137 blocks.
//   b in [0,64):    table-direct, c-pair c0=b*2, thread = co (barrier-free)
//   b in [64,3136): sent-w -> Wb bf16 transform, 1 elem/thread
//   b == 3136:      u guard rows
__global__ __launch_bounds__(256) void prep_table_kernel(
    const float* __restrict__ conv_sent_w, const float* __restrict__ conv_chr_w,
    const float* __restrict__ chr_emb, __hip_bfloat16* __restrict__ Wb,
    __hip_bfloat16* __restrict__ Tb, short* __restrict__ u_base) {
  __shared__ float s_e[2][256];
  const int b = blockIdx.x;
  const int tid = threadIdx.x;
  if (b >= 64) {
    if (b < 3136) {
      int idx = (b - 64) * 256 + tid;
      float v = conv_sent_w[idx];
      int co = idx / 1536;
      int rem = idx - co * 1536;
      int ci = rem / 3;
      int k = rem - ci * 3;
      Wb[k * 262144 + co * 512 + ci] = __float2bfloat16(v);
    } else {
      u_base[tid] = 0; u_base[tid + 256] = 0;
      u_base[4097 * 512 + tid] = 0; u_base[4097 * 512 + tid + 256] = 0;
    }
    return;
  }
  // table-direct: T[k][c][co] = sum_ci emb[c][ci] * chr_w[co][ci][k]
  // Thread co reads its own contiguous weight row (192 float4 loads, no
  // barriers after the e-stage, latency hidden by unroll).
  // ci-ascending fmaf chain per (c,k) accumulator -> bit-identical.
  const int c0 = b * 2;
  const int co = tid;
  s_e[0][tid] = chr_emb[(c0 + 0) * 256 + tid];
  s_e[1][tid] = chr_emb[(c0 + 1) * 256 + tid];
  __syncthreads();
  float acc[2][3] = {};
  const float4* wrow = (const float4*)(conv_chr_w + co * 768);
#pragma unroll 8
  for (int cq = 0; cq < 64; ++cq) {   // ci quad: ci = cq*4
    float4 f0 = wrow[cq * 3 + 0];
    float4 f1 = wrow[cq * 3 + 1];
    float4 f2 = wrow[cq * 3 + 2];
    int ci = cq * 4;
    // ci+0
    {
      float e0 = s_e[0][ci + 0], e1 = s_e[1][ci + 0];
      acc[0][0] = fmaf(e0, f0.x, acc[0][0]);
      acc[0][1] = fmaf(e0, f0.y, acc[0][1]);
      acc[0][2] = fmaf(e0, f0.z, acc[0][2]);
      acc[1][0] = fmaf(e1, f0.x, acc[1][0]);
      acc[1][1] = fmaf(e1, f0.y, acc[1][1]);
      acc[1][2] = fmaf(e1, f0.z, acc[1][2]);
    }
    // ci+1
    {
      float e0 = s_e[0][ci + 1], e1 = s_e[1][ci + 1];
      acc[0][0] = fmaf(e0, f0.w, acc[0][0]);
      acc[0][1] = fmaf(e0, f1.x, acc[0][1]);
      acc[0][2] = fmaf(e0, f1.y, acc[0][2]);
      acc[1][0] = fmaf(e1, f0.w, acc[1][0]);
      acc[1][1] = fmaf(e1, f1.x, acc[1][1]);
      acc[1][2] = fmaf(e1, f1.y, acc[1][2]);
    }
    // ci+2
    {
      float e0 = s_e[0][ci + 2], e1 = s_e[1][ci + 2];
      acc[0][0] = fmaf(e0, f1.z, acc[0][0]);
      acc[0][1] = fmaf(e0, f1.w, acc[0][1]);
      acc[0][2] = fmaf(e0, f2.x, acc[0][2]);
      acc[1][0] = fmaf(e1, f1.z, acc[1][0]);
      acc[1][1] = fmaf(e1, f1.w, acc[1][1]);
      acc[1][2] = fmaf(e1, f2.x, acc[1][2]);
    }
    // ci+3
    {
      float e0 = s_e[0][ci + 3], e1 = s_e[1][ci + 3];
      acc[0][0] = fmaf(e0, f2.y, acc[0][0]);
      acc[0][1] = fmaf(e0, f2.z, acc[0][1]);
      acc[0][2] = fmaf(e0, f2.w, acc[0][2]);
      acc[1][0] = fmaf(e1, f2.y, acc[1][0]);
      acc[1][1] = fmaf(e1, f2.z, acc[1][1]);
      acc[1][2] = fmaf(e1, f2.w, acc[1][2]);
    }
  }
  const int tbase = ((co >> 6) * 3) * 8192 + (co & 63);
#pragma unroll
  for (int k = 0; k < 3; ++k) {
    Tb[tbase + k * 8192 + (c0 + 0) * 64] = __float2bfloat16(acc[0][k]);
    Tb[tbase + k * 8192 + (c0 + 1) * 64] = __float2bfloat16(acc[1][k]);
  }
}

// K2: char conv + word-emb gather. 512 blocks (ct = b>>7, 32-word chunk),
// 2 blocks/CU (52.4 KB LDS). Conv reads table as paired-co b32 loads:
// lane = co-pair (32 lanes), half-waves = 2 words in flight.
__global__ __launch_bounds__(256) void char_word_kernel(
    const int* __restrict__ words, const int* __restrict__ wic,
    const __hip_bfloat16* __restrict__ Tb, const float* __restrict__ word_emb,
    const float* __restrict__ bias, __hip_bfloat16* __restrict__ u0) {
  __shared__ short sT[3 * 128 * 64];   // 48 KB
  __shared__ int s_wic[32 * 32];       // 4 KB
  __shared__ int s_wid[32];
  const int ct = blockIdx.x >> 7;
  const int w0 = (blockIdx.x & 127) * 32;
  const int tid = threadIdx.x;
  {
    const uint4* src = (const uint4*)((const short*)Tb + ct * 24576);
    uint4* dst = (uint4*)sT;
#pragma unroll
    for (int i = 0; i < 12; ++i) dst[tid + i * 256] = src[tid + i * 256];
    ((int4*)s_wic)[tid] = ((const int4*)(wic + w0 * 32))[tid];
    if (tid < 32) s_wid[tid] = words[w0 + tid];
  }
  __syncthreads();
  // word-emb gather: 4 slots x 8 words, coalesced 256B per word
  {
    const int co_l = tid & 63, slot = tid >> 6;
#pragma unroll
    for (int wi = 0; wi < 8; ++wi) {
      int wl = slot * 8 + wi;
      u0[(w0 + wl) * ND2 + ct * 64 + co_l] =
          __float2bfloat16(word_emb[s_wid[wl] * ND + ct * 64 + co_l]);
    }
  }
  const int wave = tid >> 6, lane = tid & 63;
  const int half = lane >> 5, co2 = (lane & 31) * 2;
  const float2 bb = *(const float2*)&bias[ct * 64 + co2];
  const short* T0p = sT;
  const short* T1p = sT + 8192;
  const short* T2p = sT + 16384;
#pragma unroll
  for (int p = 0; p < 4; ++p) {
    const int wl = wave * 8 + p * 2 + half;
    // pull this word's 32 char ids into registers (8x ds_read_b128)
    int chv[32];
    const int4* c4 = (const int4*)(s_wic + wl * 32);
#pragma unroll
    for (int j = 0; j < 8; ++j) {
      int4 cc = c4[j];
      chv[4 * j + 0] = cc.x; chv[4 * j + 1] = cc.y;
      chv[4 * j + 2] = cc.z; chv[4 * j + 3] = cc.w;
    }
    float m0 = -INFINITY, m1 = -INFINITY;
#pragma unroll
    for (int t = 0; t < NL; ++t) {
      // same per-co add order as before: T1, then T0, then T2 -> bit-exact
      unsigned v1 = *(const unsigned*)&T1p[chv[t] * 64 + co2];
      float s0 = bitsf(v1 << 16);
      float s1 = bitsf(v1 & 0xffff0000u);
      if (t > 0) {
        unsigned v0 = *(const unsigned*)&T0p[chv[t - 1] * 64 + co2];
        s0 += bitsf(v0 << 16);
        s1 += bitsf(v0 & 0xffff0000u);
      }
      if (t < NL - 1) {
        unsigned v2 = *(const unsigned*)&T2p[chv[t + 1] * 64 + co2];
        s0 += bitsf(v2 << 16);
        s1 += bitsf(v2 & 0xffff0000u);
      }
      m0 = fmaxf(m0, s0);
      m1 = fmaxf(m1, s1);
    }
    __hip_bfloat162 hh;
    hh.x = __float2bfloat16(m0 + bb.x);
    hh.y = __float2bfloat16(m1 + bb.y);
    *(__hip_bfloat162*)&u0[(w0 + wl) * ND2 + ND + ct * 64 + co2] = hh;
  }
}

// K3: sentence conv GEMM (round-0 proven: 512 blocks, 2/CU, 0-conflict swizzle)
__global__ __launch_bounds__(256, 2) void sent_conv_mfma(
    const __hip_bfloat16* __restrict__ u0,
    const __hip_bfloat16* __restrict__ Wb,
    float* __restrict__ partial) {
  __shared__ short As[64 * 64];
  __shared__ short Bs[64 * 64];
  __shared__ float sm[4][32];
  const int tid = threadIdx.x;
  const int t0 = blockIdx.x * 64;
  const int co0 = blockIdx.y * 64;
  const int wave = tid >> 6, lane = tid & 63;
  const int wy = wave >> 1, wx = wave & 1;
  const int m = lane & 15, q = lane >> 4;

  floatx4 acc[2][2];
#pragma unroll
  for (int i = 0; i < 2; ++i)
#pragma unroll
    for (int j = 0; j < 2; ++j) acc[i][j] = (floatx4){0.f, 0.f, 0.f, 0.f};

  int aoff[2][2], boff[2][2];
#pragma unroll
  for (int kk = 0; kk < 2; ++kk) {
#pragma unroll
    for (int i = 0; i < 2; ++i) {
      int row = wy * 32 + i * 16 + m;
      aoff[kk][i] = row * 64 + (((kk * 4 + q) ^ (row & 7)) * 8);
      row = wx * 32 + i * 16 + m;
      boff[kk][i] = row * 64 + (((kk * 4 + q) ^ (row & 7)) * 8);
    }
  }

  const int sc = tid & 7, sr = tid >> 3;
  const int swc = (sc ^ (sr & 7)) * 8;
  const short* WbS = (const short*)Wb;
  const short* uS = (const short*)u0;

  for (int s = 0; s < 24; ++s) {
    int k = s >> 3, ci0 = (s & 7) << 6;
    const short* WbK = WbS + k * 262144 + (co0 + sr) * 512 + ci0 + sc * 8;
    const short* uK = uS + (t0 + sr + k - 1) * 512 + ci0 + sc * 8;
    uint4 a0 = *(const uint4*)(WbK);
    uint4 a1 = *(const uint4*)(WbK + 32 * 512);
    uint4 b0 = *(const uint4*)(uK);
    uint4 b1 = *(const uint4*)(uK + 32 * 512);
    *(uint4*)&As[sr * 64 + swc] = a0;
    *(uint4*)&As[(sr + 32) * 64 + swc] = a1;
    *(uint4*)&Bs[sr * 64 + swc] = b0;
    *(uint4*)&Bs[(sr + 32) * 64 + swc] = b1;
    __syncthreads();
#pragma unroll
    for (int kk = 0; kk < 2; ++kk) {
      short8 av0 = *(const short8*)&As[aoff[kk][0]];
      short8 av1 = *(const short8*)&As[aoff[kk][1]];
      short8 bv0 = *(const short8*)&Bs[boff[kk][0]];
      short8 bv1 = *(const short8*)&Bs[boff[kk][1]];
      acc[0][0] = __builtin_amdgcn_mfma_f32_16x16x32_bf16(av0, bv0, acc[0][0], 0, 0, 0);
      acc[0][1] = __builtin_amdgcn_mfma_f32_16x16x32_bf16(av0, bv1, acc[0][1], 0, 0, 0);
      acc[1][0] = __builtin_amdgcn_mfma_f32_16x16x32_bf16(av1, bv0, acc[1][0], 0, 0, 0);
      acc[1][1] = __builtin_amdgcn_mfma_f32_16x16x32_bf16(av1, bv1, acc[1][1], 0, 0, 0);
    }
    __syncthreads();
  }

#pragma unroll
  for (int i = 0; i < 2; ++i)
#pragma unroll
    for (int r = 0; r < 4; ++r) {
      float x = fmaxf(acc[i][0][r], acc[i][1][r]);
#pragma unroll
      for (int off = 1; off < 16; off <<= 1)
        x = fmaxf(x, __shfl_xor(x, off, 64));
      if (m == 0) sm[wave][i * 16 + q * 4 + r] = x;
    }
  __syncthreads();
  if (tid < 64) {
    int whalf = tid >> 5;
    float v = fmaxf(sm[whalf * 2 + 0][tid & 31], sm[whalf * 2 + 1][tid & 31]);
    partial[(co0 + tid) * 64 + blockIdx.x] = v;
  }
}

// K4: fc1 with fused r-reduction. grid 128 x 512 threads.
__global__ __launch_bounds__(512) void fc1_kernel(
    const float* __restrict__ partial, const float* __restrict__ bs,
    const float* __restrict__ w1, const float* __restrict__ b1,
    float* __restrict__ h) {
  __shared__ float s_r[512];
  int tid = threadIdx.x;
  {
    const float4* p = (const float4*)(partial + tid * 64);
    float mm = -INFINITY;
#pragma unroll
    for (int j = 0; j < 16; ++j) {
      float4 v = p[j];
      mm = fmaxf(mm, fmaxf(fmaxf(v.x, v.y), fmaxf(v.z, v.w)));
    }
    s_r[tid] = mm + bs[tid];
  }
  __syncthreads();
  int wave = tid >> 6, lane = tid & 63;
  int o = blockIdx.x * 8 + wave;
  const float4* wv = (const float4*)(w1 + o * 512 + lane * 8);
  const float4* rv = (const float4*)(s_r + lane * 8);
  float4 w0 = wv[0], w1v = wv[1];
  float4 r0 = rv[0], r1 = rv[1];
  float acc = w0.x * r0.x + w0.y * r0.y + w0.z * r0.z + w0.w * r0.w +
              w1v.x * r1.x + w1v.y * r1.y + w1v.z * r1.z + w1v.w * r1.w;
#pragma unroll
  for (int off = 32; off >= 1; off >>= 1) acc += __shfl_down(acc, off, 64);
  if (lane == 0) h[o] = tanhf(acc + b1[o]);
}

__global__ __launch_bounds__(128) void fc2_kernel(
    const float* __restrict__ h, const float* __restrict__ w2,
    const float* __restrict__ b2, float* __restrict__ out) {
  int tid = threadIdx.x;
  int o = tid >> 6;
  int lane = tid & 63;
  float acc = 0.f;
#pragma unroll
  for (int j = 0; j < 16; ++j)
    acc = fmaf(w2[o * 1024 + lane + j * 64], h[lane + j * 64], acc);
#pragma unroll
  for (int off = 32; off >= 1; off >>= 1) acc += __shfl_down(acc, off, 64);
  if (lane == 0) out[o] = acc + b2[o];
}

extern "C" void kernel_launch(void* const* d_in, const int* in_sizes, int n_in,
                              void* d_out, int out_size, void* d_ws, size_t ws_size,
                              hipStream_t stream) {
  const int*   words       = (const int*)d_in[0];
  const int*   wic         = (const int*)d_in[1];
  const float* word_emb    = (const float*)d_in[2];
  const float* chr_emb     = (const float*)d_in[3];
  const float* conv_chr_w  = (const float*)d_in[4];
  const float* conv_chr_b  = (const float*)d_in[5];
  const float* conv_sent_w = (const float*)d_in[6];
  const float* conv_sent_b = (const float*)d_in[7];
  const float* w1          = (const float*)d_in[8];
  const float* b1          = (const float*)d_in[9];
  const float* w2          = (const float*)d_in[10];
  const float* b2          = (const float*)d_in[11];
  float* out = (float*)d_out;

  float* ws    = (float*)d_ws;
  float* part  = ws;                        // 32768 f
  float* h_buf = part + 32768;              // 1024 f
  short* Tb    = (short*)(h_buf + 1024);    // 98304 bf16
  short* u_base = Tb + 98304;               // 4098*512 bf16
  __hip_bfloat16* u0 = (__hip_bfloat16*)(u_base + 512);
  __hip_bfloat16* Wb = (__hip_bfloat16*)(u_base + 4098 * 512);

  prep_table_kernel<<<3137, 256, 0, stream>>>(conv_sent_w, conv_chr_w, chr_emb,
                                              Wb, (__hip_bfloat16*)Tb, u_base);
  char_word_kernel<<<512, 256, 0, stream>>>(words, wic, (const __hip_bfloat16*)Tb,
                                            word_emb, conv_chr_b, u0);
  sent_conv_mfma<<<dim3(64, 8), 256, 0, stream>>>(u0, Wb, part);
  fc1_kernel<<<128, 512, 0, stream>>>(part, conv_sent_b, w1, b1, h_buf);
  fc2_kernel<<<1, 128, 0, stream>>>(h_buf, w2, b2, out);
}

// Round 4
// 158.123 us; speedup vs baseline: 1.5261x; 1.0542x over previous
//
#include <hip/hip_runtime.h>
#include <hip/hip_bf16.h>
#include <math.h>

#define NW 4096
#define NL 32
#define ND 256
#define ND2 512

typedef __attribute__((ext_vector_type(8))) short short8;
typedef __attribute__((ext_vector_type(4))) float floatx4;

__device__ inline float bitsf(unsigned u) {
  union { unsigned u; float f; } v;
  v.u = u;
  return v.f;
}

// ---------------------------------------------------------------------------
// ws layout:
//   wT    fp32 [3][256][256]                 (chr conv w, [k][ci][co])
//   part  fp32 [512][64]
//   h     fp32 [1024]
//   ctr   int  [4]                            (fc12 last-block counter)
//   Tb    bf16 [4 cotile][3 k][128 c][64 co] (char conv tables)
//   u     bf16 [4098][512]  (guard rows at both ends)
//   Wb    bf16 [3][512 co][512 ci]           (sent conv w)
//
// R3 lesson: table-direct from conv_chr_w is either barrier-serial (R2) or
// uncoalesced (R3) at 1 wave/SIMD — the wT transpose pair (R0) is the only
// structure that is both coalesced and latency-pipelined. Reverted to it.
// ---------------------------------------------------------------------------

// K1: prep: sent-w transpose->bf16, chr-w transpose->wT, guard zero, ctr=0.
// 3841 blocks.
__global__ __launch_bounds__(256) void prep_kernel(
    const float* __restrict__ conv_sent_w, const float* __restrict__ conv_chr_w,
    float* __restrict__ wT, __hip_bfloat16* __restrict__ Wb,
    short* __restrict__ u_base, int* __restrict__ ctr) {
  int b = blockIdx.x;
  int tid = threadIdx.x;
  if (b < 3072) {                         // sent w: 786432 elems
    int idx = b * 256 + tid;
    float v = conv_sent_w[idx];
    int co = idx / 1536;
    int rem = idx - co * 1536;
    int ci = rem / 3;
    int k = rem - ci * 3;
    Wb[k * 262144 + co * 512 + ci] = __float2bfloat16(v);
  } else if (b < 3840) {                  // chr w: 196608 elems
    int idx = (b - 3072) * 256 + tid;
    float v = conv_chr_w[idx];
    int co = idx / 768;
    int rem = idx - co * 768;
    int ci = rem / 3;
    int k = rem - ci * 3;
    wT[k * 65536 + ci * 256 + co] = v;
  } else {                                // guard rows (t=-1, t=4096) + ctr
    u_base[tid] = 0;
    u_base[tid + 256] = 0;
    u_base[4097 * 512 + tid] = 0;
    u_base[4097 * 512 + tid + 256] = 0;
    if (tid == 0) ctr[0] = 0;
  }
}

// K2: T tables in bf16, layout [cotile][k][c][64co]
// grid 96: k = b>>5, c0 = (b&31)*4 ; 256 threads = co  (R0 proven)
__global__ __launch_bounds__(256) void table_kernel(
    const float* __restrict__ chr_emb, const float* __restrict__ wT,
    __hip_bfloat16* __restrict__ Tb) {
  __shared__ float s_e[4][256];
  int k = blockIdx.x >> 5;
  int c0 = (blockIdx.x & 31) * 4;
  int co = threadIdx.x;
#pragma unroll
  for (int j = 0; j < 4; ++j) s_e[j][co] = chr_emb[(c0 + j) * 256 + co];
  __syncthreads();
  const float* wk = wT + k * 65536;
  float a0 = 0.f, a1 = 0.f, a2 = 0.f, a3 = 0.f;
#pragma unroll 8
  for (int ci = 0; ci < 256; ++ci) {
    float w = wk[ci * 256 + co];
    a0 = fmaf(s_e[0][ci], w, a0);
    a1 = fmaf(s_e[1][ci], w, a1);
    a2 = fmaf(s_e[2][ci], w, a2);
    a3 = fmaf(s_e[3][ci], w, a3);
  }
  int base = ((co >> 6) * 3 + k) * 8192 + (co & 63);
  Tb[base + (c0 + 0) * 64] = __float2bfloat16(a0);
  Tb[base + (c0 + 1) * 64] = __float2bfloat16(a1);
  Tb[base + (c0 + 2) * 64] = __float2bfloat16(a2);
  Tb[base + (c0 + 3) * 64] = __float2bfloat16(a3);
}

// K3: char conv + word-emb gather. 512 blocks (ct = b>>7, 32-word chunk),
// 2 blocks/CU (52.4 KB LDS). Conv reads table as paired-co b32 loads:
// lane = co-pair (32 lanes), half-waves = 2 words in flight.
__global__ __launch_bounds__(256) void char_word_kernel(
    const int* __restrict__ words, const int* __restrict__ wic,
    const __hip_bfloat16* __restrict__ Tb, const float* __restrict__ word_emb,
    const float* __restrict__ bias, __hip_bfloat16* __restrict__ u0) {
  __shared__ short sT[3 * 128 * 64];   // 48 KB
  __shared__ int s_wic[32 * 32];       // 4 KB
  __shared__ int s_wid[32];
  const int ct = blockIdx.x >> 7;
  const int w0 = (blockIdx.x & 127) * 32;
  const int tid = threadIdx.x;
  {
    const uint4* src = (const uint4*)((const short*)Tb + ct * 24576);
    uint4* dst = (uint4*)sT;
#pragma unroll
    for (int i = 0; i < 12; ++i) dst[tid + i * 256] = src[tid + i * 256];
    ((int4*)s_wic)[tid] = ((const int4*)(wic + w0 * 32))[tid];
    if (tid < 32) s_wid[tid] = words[w0 + tid];
  }
  __syncthreads();
  // word-emb gather: 4 slots x 8 words, coalesced 256B per word
  {
    const int co_l = tid & 63, slot = tid >> 6;
#pragma unroll
    for (int wi = 0; wi < 8; ++wi) {
      int wl = slot * 8 + wi;
      u0[(w0 + wl) * ND2 + ct * 64 + co_l] =
          __float2bfloat16(word_emb[s_wid[wl] * ND + ct * 64 + co_l]);
    }
  }
  const int wave = tid >> 6, lane = tid & 63;
  const int half = lane >> 5, co2 = (lane & 31) * 2;
  const float2 bb = *(const float2*)&bias[ct * 64 + co2];
  const short* T0p = sT;
  const short* T1p = sT + 8192;
  const short* T2p = sT + 16384;
#pragma unroll
  for (int p = 0; p < 4; ++p) {
    const int wl = wave * 8 + p * 2 + half;
    // pull this word's 32 char ids into registers (8x ds_read_b128)
    int chv[32];
    const int4* c4 = (const int4*)(s_wic + wl * 32);
#pragma unroll
    for (int j = 0; j < 8; ++j) {
      int4 cc = c4[j];
      chv[4 * j + 0] = cc.x; chv[4 * j + 1] = cc.y;
      chv[4 * j + 2] = cc.z; chv[4 * j + 3] = cc.w;
    }
    float m0 = -INFINITY, m1 = -INFINITY;
#pragma unroll
    for (int t = 0; t < NL; ++t) {
      // same per-co add order as before: T1, then T0, then T2 -> bit-exact
      unsigned v1 = *(const unsigned*)&T1p[chv[t] * 64 + co2];
      float s0 = bitsf(v1 << 16);
      float s1 = bitsf(v1 & 0xffff0000u);
      if (t > 0) {
        unsigned v0 = *(const unsigned*)&T0p[chv[t - 1] * 64 + co2];
        s0 += bitsf(v0 << 16);
        s1 += bitsf(v0 & 0xffff0000u);
      }
      if (t < NL - 1) {
        unsigned v2 = *(const unsigned*)&T2p[chv[t + 1] * 64 + co2];
        s0 += bitsf(v2 << 16);
        s1 += bitsf(v2 & 0xffff0000u);
      }
      m0 = fmaxf(m0, s0);
      m1 = fmaxf(m1, s1);
    }
    __hip_bfloat162 hh;
    hh.x = __float2bfloat16(m0 + bb.x);
    hh.y = __float2bfloat16(m1 + bb.y);
    *(__hip_bfloat162*)&u0[(w0 + wl) * ND2 + ND + ct * 64 + co2] = hh;
  }
}

// K4: sentence conv GEMM (round-0 proven: 512 blocks, 2/CU, 0-conflict swizzle)
__global__ __launch_bounds__(256, 2) void sent_conv_mfma(
    const __hip_bfloat16* __restrict__ u0,
    const __hip_bfloat16* __restrict__ Wb,
    float* __restrict__ partial) {
  __shared__ short As[64 * 64];
  __shared__ short Bs[64 * 64];
  __shared__ float sm[4][32];
  const int tid = threadIdx.x;
  const int t0 = blockIdx.x * 64;
  const int co0 = blockIdx.y * 64;
  const int wave = tid >> 6, lane = tid & 63;
  const int wy = wave >> 1, wx = wave & 1;
  const int m = lane & 15, q = lane >> 4;

  floatx4 acc[2][2];
#pragma unroll
  for (int i = 0; i < 2; ++i)
#pragma unroll
    for (int j = 0; j < 2; ++j) acc[i][j] = (floatx4){0.f, 0.f, 0.f, 0.f};

  int aoff[2][2], boff[2][2];
#pragma unroll
  for (int kk = 0; kk < 2; ++kk) {
#pragma unroll
    for (int i = 0; i < 2; ++i) {
      int row = wy * 32 + i * 16 + m;
      aoff[kk][i] = row * 64 + (((kk * 4 + q) ^ (row & 7)) * 8);
      row = wx * 32 + i * 16 + m;
      boff[kk][i] = row * 64 + (((kk * 4 + q) ^ (row & 7)) * 8);
    }
  }

  const int sc = tid & 7, sr = tid >> 3;
  const int swc = (sc ^ (sr & 7)) * 8;
  const short* WbS = (const short*)Wb;
  const short* uS = (const short*)u0;

  for (int s = 0; s < 24; ++s) {
    int k = s >> 3, ci0 = (s & 7) << 6;
    const short* WbK = WbS + k * 262144 + (co0 + sr) * 512 + ci0 + sc * 8;
    const short* uK = uS + (t0 + sr + k - 1) * 512 + ci0 + sc * 8;
    uint4 a0 = *(const uint4*)(WbK);
    uint4 a1 = *(const uint4*)(WbK + 32 * 512);
    uint4 b0 = *(const uint4*)(uK);
    uint4 b1 = *(const uint4*)(uK + 32 * 512);
    *(uint4*)&As[sr * 64 + swc] = a0;
    *(uint4*)&As[(sr + 32) * 64 + swc] = a1;
    *(uint4*)&Bs[sr * 64 + swc] = b0;
    *(uint4*)&Bs[(sr + 32) * 64 + swc] = b1;
    __syncthreads();
#pragma unroll
    for (int kk = 0; kk < 2; ++kk) {
      short8 av0 = *(const short8*)&As[aoff[kk][0]];
      short8 av1 = *(const short8*)&As[aoff[kk][1]];
      short8 bv0 = *(const short8*)&Bs[boff[kk][0]];
      short8 bv1 = *(const short8*)&Bs[boff[kk][1]];
      acc[0][0] = __builtin_amdgcn_mfma_f32_16x16x32_bf16(av0, bv0, acc[0][0], 0, 0, 0);
      acc[0][1] = __builtin_amdgcn_mfma_f32_16x16x32_bf16(av0, bv1, acc[0][1], 0, 0, 0);
      acc[1][0] = __builtin_amdgcn_mfma_f32_16x16x32_bf16(av1, bv0, acc[1][0], 0, 0, 0);
      acc[1][1] = __builtin_amdgcn_mfma_f32_16x16x32_bf16(av1, bv1, acc[1][1], 0, 0, 0);
    }
    __syncthreads();
  }

#pragma unroll
  for (int i = 0; i < 2; ++i)
#pragma unroll
    for (int r = 0; r < 4; ++r) {
      float x = fmaxf(acc[i][0][r], acc[i][1][r]);
#pragma unroll
      for (int off = 1; off < 16; off <<= 1)
        x = fmaxf(x, __shfl_xor(x, off, 64));
      if (m == 0) sm[wave][i * 16 + q * 4 + r] = x;
    }
  __syncthreads();
  if (tid < 64) {
    int whalf = tid >> 5;
    float v = fmaxf(sm[whalf * 2 + 0][tid & 31], sm[whalf * 2 + 1][tid & 31]);
    partial[(co0 + tid) * 64 + blockIdx.x] = v;
  }
}

// K5: fc1 + fc2 fused. grid 128 x 512 threads; last-arriving block runs fc2.
// Publication sequence (syncthreads -> tid0 agent-RELEASE fetch_add; consumer:
// agent-ACQUIRE fence -> reads) is the R1-validated pattern.
__global__ __launch_bounds__(512) void fc12_kernel(
    const float* __restrict__ partial, const float* __restrict__ bs,
    const float* __restrict__ w1, const float* __restrict__ b1,
    const float* __restrict__ w2, const float* __restrict__ b2,
    float* __restrict__ h, int* __restrict__ ctr, float* __restrict__ out) {
  __shared__ float s_r[512];
  __shared__ int s_last;
  int tid = threadIdx.x;
  {
    const float4* p = (const float4*)(partial + tid * 64);
    float mm = -INFINITY;
#pragma unroll
    for (int j = 0; j < 16; ++j) {
      float4 v = p[j];
      mm = fmaxf(mm, fmaxf(fmaxf(v.x, v.y), fmaxf(v.z, v.w)));
    }
    s_r[tid] = mm + bs[tid];
  }
  __syncthreads();
  int wave = tid >> 6, lane = tid & 63;
  int o = blockIdx.x * 8 + wave;
  const float4* wv = (const float4*)(w1 + o * 512 + lane * 8);
  const float4* rv = (const float4*)(s_r + lane * 8);
  float4 w0 = wv[0], w1v = wv[1];
  float4 r0 = rv[0], r1 = rv[1];
  float acc = w0.x * r0.x + w0.y * r0.y + w0.z * r0.z + w0.w * r0.w +
              w1v.x * r1.x + w1v.y * r1.y + w1v.z * r1.z + w1v.w * r1.w;
#pragma unroll
  for (int off = 32; off >= 1; off >>= 1) acc += __shfl_down(acc, off, 64);
  if (lane == 0) h[o] = tanhf(acc + b1[o]);
  // publish h; last block to arrive computes fc2
  __syncthreads();   // drains vmcnt for the whole block's h stores
  if (tid == 0) {
    int old = __hip_atomic_fetch_add(ctr, 1, __ATOMIC_RELEASE,
                                     __HIP_MEMORY_SCOPE_AGENT);
    s_last = (old == 127) ? 1 : 0;
  }
  __syncthreads();
  if (s_last) {
    __builtin_amdgcn_fence(__ATOMIC_ACQUIRE, "agent");
    if (tid < 128) {
      int o2 = tid >> 6;
      int lane2 = tid & 63;
      float acc2 = 0.f;
#pragma unroll
      for (int j = 0; j < 16; ++j)
        acc2 = fmaf(w2[o2 * 1024 + lane2 + j * 64], h[lane2 + j * 64], acc2);
#pragma unroll
      for (int off = 32; off >= 1; off >>= 1) acc2 += __shfl_down(acc2, off, 64);
      if (lane2 == 0) out[o2] = acc2 + b2[o2];
    }
  }
}

extern "C" void kernel_launch(void* const* d_in, const int* in_sizes, int n_in,
                              void* d_out, int out_size, void* d_ws, size_t ws_size,
                              hipStream_t stream) {
  const int*   words       = (const int*)d_in[0];
  const int*   wic         = (const int*)d_in[1];
  const float* word_emb    = (const float*)d_in[2];
  const float* chr_emb     = (const float*)d_in[3];
  const float* conv_chr_w  = (const float*)d_in[4];
  const float* conv_chr_b  = (const float*)d_in[5];
  const float* conv_sent_w = (const float*)d_in[6];
  const float* conv_sent_b = (const float*)d_in[7];
  const float* w1          = (const float*)d_in[8];
  const float* b1          = (const float*)d_in[9];
  const float* w2          = (const float*)d_in[10];
  const float* b2          = (const float*)d_in[11];
  float* out = (float*)d_out;

  float* ws    = (float*)d_ws;
  float* wT    = ws;                        // 196608 f
  float* part  = wT + 196608;               // 32768 f
  float* h_buf = part + 32768;              // 1024 f
  int*   ctr   = (int*)(h_buf + 1024);      // 4 ints
  short* Tb    = (short*)(ctr + 4);         // 98304 bf16
  short* u_base = Tb + 98304;               // 4098*512 bf16
  __hip_bfloat16* u0 = (__hip_bfloat16*)(u_base + 512);
  __hip_bfloat16* Wb = (__hip_bfloat16*)(u_base + 4098 * 512);

  prep_kernel<<<3841, 256, 0, stream>>>(conv_sent_w, conv_chr_w, wT, Wb,
                                        u_base, ctr);
  table_kernel<<<96, 256, 0, stream>>>(chr_emb, wT, (__hip_bfloat16*)Tb);
  char_word_kernel<<<512, 256, 0, stream>>>(words, wic, (const __hip_bfloat16*)Tb,
                                            word_emb, conv_chr_b, u0);
  sent_conv_mfma<<<dim3(64, 8), 256, 0, stream>>>(u0, Wb, part);
  fc12_kernel<<<128, 512, 0, stream>>>(part, conv_sent_b, w1, b1, w2, b2,
                                       h_buf, ctr, out);
}